// Round 8
// baseline (287.123 us; speedup 1.0000x reference)
//
#include <hip/hip_runtime.h>
#include <hip/hip_bf16.h>
#include <hip/hip_fp16.h>

#define N_NODES 50000
#define N_EDGES 400000
#define D 16
#define HID 64

#define SCAN_B 256
#define SCAN_G ((N_NODES + SCAN_B - 1) / SCAN_B)   // 196

typedef unsigned short ushort_t;

// ---------------- int-indexed workspace layout (CSR path) ----------------
#define CNT4_OFF  0                       // [4][N] replicated counts (memset 0)
#define DEG_OFF   (4 * N_NODES)           // [N] total degree
#define OFF_OFF   (5 * N_NODES)           // [N+1] CSR offsets
#define CUR_OFF   (6 * N_NODES + 1)       // [N] claim cursors
#define BS_OFF    (7 * N_NODES + 1)       // [SCAN_G] block sums
#define MSG_OFF_I (((BS_OFF + SCAN_G) + 15) & ~15) // [2E*16] fp32 msgs, 64B-aligned
#define PREP_OFF  (MSG_OFF_I + 2 * N_EDGES * D)
#define PREP_DW   (64 * 64 + 16)
#define CSR_NEEDED_BYTES ((size_t)(PREP_OFF + PREP_DW) * 4 + 64)

// ---------------- fallback (atomic) layout ----------------
#define FB_NDEG   (N_NODES)
#define FB_NACC   (N_NODES * D)
#define FB_FLAGS  (FB_NDEG + FB_NACC)

// ---------------------------------------------------------------------------
// dtype helpers
// ---------------------------------------------------------------------------
__device__ __forceinline__ float bf_bits(ushort_t us) {
    return __uint_as_float(((unsigned)us) << 16);
}
__device__ __forceinline__ float lo_bf(unsigned u) { return __uint_as_float(u << 16); }
__device__ __forceinline__ float hi_bf(unsigned u) { return __uint_as_float(u & 0xffff0000u); }
__device__ __forceinline__ ushort_t f2bf(float v) {
    unsigned u = __float_as_uint(v);
    unsigned r = (u + 0x7fffu + ((u >> 16) & 1u)) >> 16;
    return (ushort_t)r;
}
__device__ __forceinline__ float ld_f(const void* p, int idx, int f32) {
    return f32 ? ((const float*)p)[idx]
               : bf_bits(((const ushort_t*)p)[idx]);
}

__device__ __forceinline__ void load16(const void* __restrict__ p, long long base,
                                       int f32, float* o) {
    if (f32) {
        const float4* q = (const float4*)((const float*)p + base);
        float4 a = q[0], b = q[1], c = q[2], d = q[3];
        o[0]=a.x; o[1]=a.y; o[2]=a.z; o[3]=a.w;
        o[4]=b.x; o[5]=b.y; o[6]=b.z; o[7]=b.w;
        o[8]=c.x; o[9]=c.y; o[10]=c.z; o[11]=c.w;
        o[12]=d.x; o[13]=d.y; o[14]=d.z; o[15]=d.w;
    } else {
        const uint4* q = (const uint4*)((const ushort_t*)p + base);
        uint4 a = q[0], b = q[1];
        unsigned u[8] = {a.x, a.y, a.z, a.w, b.x, b.y, b.z, b.w};
#pragma unroll
        for (int k = 0; k < 8; k++) {
            o[2 * k]     = lo_bf(u[k]);
            o[2 * k + 1] = hi_bf(u[k]);
        }
    }
}

__device__ __forceinline__ void load_edge(const void* __restrict__ ei, int e, int is64,
                                          int& s, int& d) {
    if (is64) {
        const long long* p = (const long long*)ei;
        s = (int)p[e];
        d = (int)p[N_EDGES + e];
    } else {
        const int* p = (const int*)ei;
        s = p[e];
        d = p[N_EDGES + e];
    }
}

// Parallel flag detection (wave 0, ballot), per-block, no cross-block dep.
__device__ __forceinline__ void detect_flags_par(const void* x, const void* ei,
                                                 int* flags) {
    int t = threadIdx.x;
    if (t < 64) {
        const ushort_t* h = (const ushort_t*)x;
        int bad = 0;
#pragma unroll
        for (int k = 0; k < 4; k++) {
            float v = bf_bits(h[4 * t + k]);
            if (!(v == v) || fabsf(v) > 1.0e6f) bad = 1;
        }
        unsigned long long mb = __ballot(bad);
        const long long* p = (const long long*)ei;
        int bad64 = 0;
        if (t < 16) {
            long long v = p[t];
            bad64 = (v < 0 || v >= N_NODES) ? 1 : 0;
        }
        unsigned long long m64 = __ballot(bad64);
        if (t == 0) {
            flags[0] = mb ? 1 : 0;
            flags[1] = m64 ? 0 : 1;
        }
    }
}

__device__ __forceinline__ void stage_weights(
    const void* W1, const void* b1, const void* W2, const void* b2, int f32,
    float* sW1, float* sW2t, float* sb1, float* sb2)
{
    int t = threadIdx.x;
    for (int idx = t; idx < HID * 2 * D; idx += blockDim.x)
        sW1[idx] = ld_f(W1, idx, f32);
    for (int idx = t; idx < HID * D; idx += blockDim.x) {
        int j = idx / D, i = idx % D;
        sW2t[idx] = ld_f(W2, i * HID + j, f32);
    }
    if (t < HID) sb1[t] = ld_f(b1, t, f32);
    if (t < D)  sb2[t] = ld_f(b2, t, f32);
}

// ---------------------------------------------------------------------------
// Full-MLP per-edge math, f32 (safety + fallback paths) — proven op order.
// ---------------------------------------------------------------------------
__device__ __forceinline__ void edge_math_v4(
    const float* __restrict__ sW1, const float* __restrict__ sW2t,
    const float* __restrict__ sb1, const float* __restrict__ sb2,
    const float* xs, const float* xd, float coef,
    float* ms, float* md)
{
    float vs[D], vd[D];
#pragma unroll
    for (int i = 0; i < D; i++) { vs[i] = sb2[i]; vd[i] = sb2[i]; }
#pragma unroll 4
    for (int j = 0; j < HID; j++) {
        float hs = sb1[j], hd = sb1[j];
        const float4* w4 = (const float4*)&sW1[j * 2 * D];
#pragma unroll
        for (int t = 0; t < 4; t++) {
            float4 wv = w4[t];
            int k = 4 * t;
            hs = fmaf(wv.x, xs[k],     hs); hd = fmaf(wv.x, xd[k],     hd);
            hs = fmaf(wv.y, xs[k + 1], hs); hd = fmaf(wv.y, xd[k + 1], hd);
            hs = fmaf(wv.z, xs[k + 2], hs); hd = fmaf(wv.z, xd[k + 2], hd);
            hs = fmaf(wv.w, xs[k + 3], hs); hd = fmaf(wv.w, xd[k + 3], hd);
        }
#pragma unroll
        for (int t = 0; t < 4; t++) {
            float4 wv = w4[4 + t];
            int k = 4 * t;
            hs = fmaf(wv.x, xd[k],     hs); hd = fmaf(wv.x, xs[k],     hd);
            hs = fmaf(wv.y, xd[k + 1], hs); hd = fmaf(wv.y, xs[k + 1], hd);
            hs = fmaf(wv.z, xd[k + 2], hs); hd = fmaf(wv.z, xs[k + 2], hd);
            hs = fmaf(wv.w, xd[k + 3], hs); hd = fmaf(wv.w, xs[k + 3], hd);
        }
        hs = fmaxf(hs, 0.0f);
        hd = fmaxf(hd, 0.0f);
        const float4* w24 = (const float4*)&sW2t[j * D];
#pragma unroll
        for (int t = 0; t < 4; t++) {
            float4 u = w24[t];
            int i = 4 * t;
            vs[i]     = fmaf(u.x, hs, vs[i]);     vd[i]     = fmaf(u.x, hd, vd[i]);
            vs[i + 1] = fmaf(u.y, hs, vs[i + 1]); vd[i + 1] = fmaf(u.y, hd, vd[i + 1]);
            vs[i + 2] = fmaf(u.z, hs, vs[i + 2]); vd[i + 2] = fmaf(u.z, hd, vd[i + 2]);
            vs[i + 3] = fmaf(u.w, hs, vs[i + 3]); vd[i + 3] = fmaf(u.w, hd, vd[i + 3]);
        }
    }
    float ns = 0.0f, nd = 0.0f;
#pragma unroll
    for (int i = 0; i < D; i++) { ns = fmaf(vs[i], vs[i], ns); nd = fmaf(vd[i], vd[i], nd); }
    float is_ = 1.0f / fmaxf(sqrtf(ns), 1e-12f);
    float id_ = 1.0f / fmaxf(sqrtf(nd), 1e-12f);
#pragma unroll
    for (int i = 0; i < D; i++) { vs[i] *= is_; vd[i] *= id_; }
    float dot1 = 0.0f;
#pragma unroll
    for (int i = 0; i < D; i++) dot1 = fmaf(vd[i], xd[i], dot1);
#pragma unroll
    for (int i = 0; i < D; i++) ms[i] = fmaf(-2.0f * dot1, vd[i], xd[i]);
    float dot2 = 0.0f;
#pragma unroll
    for (int i = 0; i < D; i++) dot2 = fmaf(vs[i], ms[i], dot2);
#pragma unroll
    for (int i = 0; i < D; i++) ms[i] = coef * fmaf(-2.0f * dot2, vs[i], ms[i]);
    float dot3 = 0.0f;
#pragma unroll
    for (int i = 0; i < D; i++) dot3 = fmaf(vs[i], xs[i], dot3);
#pragma unroll
    for (int i = 0; i < D; i++) md[i] = fmaf(-2.0f * dot3, vs[i], xs[i]);
    float dot4 = 0.0f;
#pragma unroll
    for (int i = 0; i < D; i++) dot4 = fmaf(vd[i], md[i], dot4);
#pragma unroll
    for (int i = 0; i < D; i++) md[i] = coef * fmaf(-2.0f * dot4, vd[i], md[i]);
}

// ---------------------------------------------------------------------------
// bf16 path, TWO EDGES PER THREAD, SGPR weight table.
// The R3 j-loop's dependent {s_load 52 dwords -> waitcnt -> 128 FMA-cyc}
// left ~80 unhidden scalar-load cycles per iteration (SGPR=80: no room to
// double-buffer a row). Feeding TWO edges' chains (8 independent
// accumulators, 256 FMA-cyc) from each row halves that stall share and
// halves loop overhead. Per-edge op order identical to R3 -> same bits.
// ---------------------------------------------------------------------------
__device__ __forceinline__ void edge_math_prep2(
    const float* __restrict__ prep,
    const float* xsA, const float* xdA, float coefA,
    const float* xsB, const float* xdB, float coefB,
    float* msA, float* mdA, float* msB, float* mdB)
{
    const float* b2f = prep + 64 * 64;
    float vsA[D], vdA[D], vsB[D], vdB[D];
#pragma unroll
    for (int i = 0; i < D; i++) {
        vsA[i] = b2f[i]; vdA[i] = b2f[i];
        vsB[i] = b2f[i]; vdB[i] = b2f[i];
    }

#pragma unroll 1
    for (int j = 0; j < HID; j++) {
        const float* w = prep + (j << 6);    // uniform -> s_load
        float b1j = w[48];
        float hs0A = b1j, hs1A = 0.0f, hd0A = b1j, hd1A = 0.0f;
        float hs0B = b1j, hs1B = 0.0f, hd0B = b1j, hd1B = 0.0f;
#pragma unroll
        for (int k = 0; k < 8; k++) {        // [x_s | .] part
            hs0A = fmaf(w[k],     xsA[k],     hs0A);
            hd0A = fmaf(w[k],     xdA[k],     hd0A);
            hs1A = fmaf(w[8 + k], xsA[8 + k], hs1A);
            hd1A = fmaf(w[8 + k], xdA[8 + k], hd1A);
            hs0B = fmaf(w[k],     xsB[k],     hs0B);
            hd0B = fmaf(w[k],     xdB[k],     hd0B);
            hs1B = fmaf(w[8 + k], xsB[8 + k], hs1B);
            hd1B = fmaf(w[8 + k], xdB[8 + k], hd1B);
        }
#pragma unroll
        for (int k = 0; k < 8; k++) {        // [. | x_d] part
            hs0A = fmaf(w[16 + k], xdA[k],     hs0A);
            hd0A = fmaf(w[16 + k], xsA[k],     hd0A);
            hs1A = fmaf(w[24 + k], xdA[8 + k], hs1A);
            hd1A = fmaf(w[24 + k], xsA[8 + k], hd1A);
            hs0B = fmaf(w[16 + k], xdB[k],     hs0B);
            hd0B = fmaf(w[16 + k], xsB[k],     hd0B);
            hs1B = fmaf(w[24 + k], xdB[8 + k], hs1B);
            hd1B = fmaf(w[24 + k], xsB[8 + k], hd1B);
        }
        float hsA = fmaxf(hs0A + hs1A, 0.0f);
        float hdA = fmaxf(hd0A + hd1A, 0.0f);
        float hsB = fmaxf(hs0B + hs1B, 0.0f);
        float hdB = fmaxf(hd0B + hd1B, 0.0f);
#pragma unroll
        for (int i = 0; i < D; i++) {
            vsA[i] = fmaf(w[32 + i], hsA, vsA[i]);
            vdA[i] = fmaf(w[32 + i], hdA, vdA[i]);
            vsB[i] = fmaf(w[32 + i], hsB, vsB[i]);
            vdB[i] = fmaf(w[32 + i], hdB, vdB[i]);
        }
    }

    // epilogue A (op order = R3)
    {
        float ns = 0.0f, nd = 0.0f;
#pragma unroll
        for (int i = 0; i < D; i++) { ns = fmaf(vsA[i], vsA[i], ns); nd = fmaf(vdA[i], vdA[i], nd); }
        float is_ = 1.0f / fmaxf(sqrtf(ns), 1e-12f);
        float id_ = 1.0f / fmaxf(sqrtf(nd), 1e-12f);
#pragma unroll
        for (int i = 0; i < D; i++) { vsA[i] *= is_; vdA[i] *= id_; }
        float dot1 = 0.0f;
#pragma unroll
        for (int i = 0; i < D; i++) dot1 = fmaf(vdA[i], xdA[i], dot1);
#pragma unroll
        for (int i = 0; i < D; i++) msA[i] = fmaf(-2.0f * dot1, vdA[i], xdA[i]);
        float dot2 = 0.0f;
#pragma unroll
        for (int i = 0; i < D; i++) dot2 = fmaf(vsA[i], msA[i], dot2);
#pragma unroll
        for (int i = 0; i < D; i++) msA[i] = coefA * fmaf(-2.0f * dot2, vsA[i], msA[i]);
        float dot3 = 0.0f;
#pragma unroll
        for (int i = 0; i < D; i++) dot3 = fmaf(vsA[i], xsA[i], dot3);
#pragma unroll
        for (int i = 0; i < D; i++) mdA[i] = fmaf(-2.0f * dot3, vsA[i], xsA[i]);
        float dot4 = 0.0f;
#pragma unroll
        for (int i = 0; i < D; i++) dot4 = fmaf(vdA[i], mdA[i], dot4);
#pragma unroll
        for (int i = 0; i < D; i++) mdA[i] = coefA * fmaf(-2.0f * dot4, vdA[i], mdA[i]);
    }
    // epilogue B
    {
        float ns = 0.0f, nd = 0.0f;
#pragma unroll
        for (int i = 0; i < D; i++) { ns = fmaf(vsB[i], vsB[i], ns); nd = fmaf(vdB[i], vdB[i], nd); }
        float is_ = 1.0f / fmaxf(sqrtf(ns), 1e-12f);
        float id_ = 1.0f / fmaxf(sqrtf(nd), 1e-12f);
#pragma unroll
        for (int i = 0; i < D; i++) { vsB[i] *= is_; vdB[i] *= id_; }
        float dot1 = 0.0f;
#pragma unroll
        for (int i = 0; i < D; i++) dot1 = fmaf(vdB[i], xdB[i], dot1);
#pragma unroll
        for (int i = 0; i < D; i++) msB[i] = fmaf(-2.0f * dot1, vdB[i], xdB[i]);
        float dot2 = 0.0f;
#pragma unroll
        for (int i = 0; i < D; i++) dot2 = fmaf(vsB[i], msB[i], dot2);
#pragma unroll
        for (int i = 0; i < D; i++) msB[i] = coefB * fmaf(-2.0f * dot2, vsB[i], msB[i]);
        float dot3 = 0.0f;
#pragma unroll
        for (int i = 0; i < D; i++) dot3 = fmaf(vsB[i], xsB[i], dot3);
#pragma unroll
        for (int i = 0; i < D; i++) mdB[i] = fmaf(-2.0f * dot3, vsB[i], xsB[i]);
        float dot4 = 0.0f;
#pragma unroll
        for (int i = 0; i < D; i++) dot4 = fmaf(vdB[i], mdB[i], dot4);
#pragma unroll
        for (int i = 0; i < D; i++) mdB[i] = coefB * fmaf(-2.0f * dot4, vdB[i], mdB[i]);
    }
}

// Edge tail: claim slots + write both msgs.
__device__ __forceinline__ void write_msgs(int* __restrict__ wsI, float* __restrict__ msg,
                                           int s, int d, const float* ms, const float* md)
{
    int slot_s = atomicAdd(&wsI[CUR_OFF + s], 1);
    float4* m0 = (float4*)(msg + (long long)slot_s * D);
    m0[0] = make_float4(ms[0], ms[1], ms[2], ms[3]);
    m0[1] = make_float4(ms[4], ms[5], ms[6], ms[7]);
    m0[2] = make_float4(ms[8], ms[9], ms[10], ms[11]);
    m0[3] = make_float4(ms[12], ms[13], ms[14], ms[15]);
    int slot_d = atomicAdd(&wsI[CUR_OFF + d], 1);
    float4* m1 = (float4*)(msg + (long long)slot_d * D);
    m1[0] = make_float4(md[0], md[1], md[2], md[3]);
    m1[1] = make_float4(md[4], md[5], md[6], md[7]);
    m1[2] = make_float4(md[8], md[9], md[10], md[11]);
    m1[3] = make_float4(md[12], md[13], md[14], md[15]);
}

// Weight-table packing. bf16 interpretation; f32 path ignores it.
__device__ __forceinline__ void pack_prep(const void* W1, const void* b1,
                                          const void* W2, const void* b2,
                                          int* __restrict__ wsI)
{
    float* pf = (float*)(wsI + PREP_OFF);
    const ushort_t* W1b = (const ushort_t*)W1;
    const ushort_t* W2b = (const ushort_t*)W2;
    const ushort_t* b1b = (const ushort_t*)b1;
    const ushort_t* b2b = (const ushort_t*)b2;
    for (int idx = threadIdx.x; idx < 64 * 64; idx += 256) {
        int j = idx >> 6, w = idx & 63;
        float val = 0.0f;
        if (w < 32)      val = bf_bits(W1b[j * 32 + w]);
        else if (w < 48) val = bf_bits(W2b[(w - 32) * HID + j]);
        else if (w == 48) val = bf_bits(b1b[j]);
        pf[idx] = val;
    }
    if (threadIdx.x < D)
        pf[64 * 64 + threadIdx.x] = bf_bits(b2b[threadIdx.x]);
}

// Gather body for one (node, quad) pair.
__device__ __forceinline__ void gather_node(int n, int c, int f32,
                                            const int* __restrict__ wsI,
                                            const void* __restrict__ x,
                                            void* __restrict__ out)
{
    const int* off = wsI + OFF_OFF;
    const float4* msg4 = (const float4*)(wsI + MSG_OFF_I);

    int beg = off[n], end = off[n + 1];
    float4 a = make_float4(0.0f, 0.0f, 0.0f, 0.0f);
    int it = beg;
    for (; it + 2 <= end; it += 2) {
        float4 u = msg4[(long long)it * 4 + c];
        float4 v = msg4[(long long)(it + 1) * 4 + c];
        a.x += u.x + v.x; a.y += u.y + v.y; a.z += u.z + v.z; a.w += u.w + v.w;
    }
    if (it < end) {
        float4 u = msg4[(long long)it * 4 + c];
        a.x += u.x; a.y += u.y; a.z += u.z; a.w += u.w;
    }

    long long xb = (long long)n * D + 4 * c;
    float4 xv;
    if (f32) {
        xv = *(const float4*)((const float*)x + xb);
    } else {
        uint2 u = *(const uint2*)((const ushort_t*)x + xb);
        xv.x = lo_bf(u.x); xv.y = hi_bf(u.x);
        xv.z = lo_bf(u.y); xv.w = hi_bf(u.y);
    }
    float4 r;
    r.x = fmaxf(xv.x + a.x, 0.0f);
    r.y = fmaxf(xv.y + a.y, 0.0f);
    r.z = fmaxf(xv.z + a.z, 0.0f);
    r.w = fmaxf(xv.w + a.w, 0.0f);
    if (f32) {
        *(float4*)((float*)out + xb) = r;
    } else {
        uint2 o;
        o.x = (unsigned)f2bf(r.x) | ((unsigned)f2bf(r.y) << 16);
        o.y = (unsigned)f2bf(r.z) | ((unsigned)f2bf(r.w) << 16);
        *(uint2*)((ushort_t*)out + xb) = o;
    }
}

// ===========================================================================
// CSR pipeline (R6-proven)
// ===========================================================================
__global__ void csr_count_kernel(const void* __restrict__ ei,
                                 const void* __restrict__ x,
                                 const void* __restrict__ W1,
                                 const void* __restrict__ b1,
                                 const void* __restrict__ W2,
                                 const void* __restrict__ b2,
                                 int* __restrict__ wsI) {
    __shared__ int sfl[2];
    detect_flags_par(x, ei, sfl);
    __syncthreads();
    int i64 = sfl[1];

    if (blockIdx.x == 0) pack_prep(W1, b1, W2, b2, wsI);

    int e = blockIdx.x * blockDim.x + threadIdx.x;
    if (e >= N_EDGES) return;
    int s, d;
    load_edge(ei, e, i64, s, d);
    int r = (e & 3) * N_NODES;
    atomicAdd(&wsI[CNT4_OFF + r + s], 1);
    atomicAdd(&wsI[CNT4_OFF + r + d], 1);
}

__global__ __launch_bounds__(SCAN_B) void csr_scan1_kernel(int* __restrict__ wsI) {
    __shared__ int sm[SCAN_B];
    int t = threadIdx.x;
    int g = blockIdx.x * SCAN_B + t;
    int c = 0;
    if (g < N_NODES) {
        c = wsI[CNT4_OFF + g] + wsI[CNT4_OFF + N_NODES + g]
          + wsI[CNT4_OFF + 2 * N_NODES + g] + wsI[CNT4_OFF + 3 * N_NODES + g];
        wsI[DEG_OFF + g] = c;
    }
    sm[t] = c;
    __syncthreads();
    for (int st = SCAN_B / 2; st > 0; st >>= 1) {
        if (t < st) sm[t] += sm[t + st];
        __syncthreads();
    }
    if (t == 0) wsI[BS_OFF + blockIdx.x] = sm[0];
}

__global__ __launch_bounds__(SCAN_B) void csr_scan3_kernel(int* __restrict__ wsI) {
    __shared__ int sB[SCAN_B];
    __shared__ int sm[SCAN_B];
    int t = threadIdx.x;
    int bsv = (t < SCAN_G) ? wsI[BS_OFF + t] : 0;
    sB[t] = bsv;
    __syncthreads();
    for (int st = 1; st < SCAN_B; st <<= 1) {
        int u = (t >= st) ? sB[t - st] : 0;
        __syncthreads();
        sB[t] += u;
        __syncthreads();
    }
    int blockBase = sB[blockIdx.x] - wsI[BS_OFF + blockIdx.x];

    int g = blockIdx.x * SCAN_B + t;
    int c = (g < N_NODES) ? wsI[DEG_OFF + g] : 0;
    sm[t] = c;
    __syncthreads();
    for (int st = 1; st < SCAN_B; st <<= 1) {
        int u = (t >= st) ? sm[t - st] : 0;
        __syncthreads();
        sm[t] += u;
        __syncthreads();
    }
    int excl = sm[t] - c + blockBase;
    if (g < N_NODES) {
        wsI[OFF_OFF + g] = excl;
        wsI[CUR_OFF + g] = excl;
        if (g == N_NODES - 1) wsI[OFF_OFF + N_NODES] = excl + c;
    }
}

// Edge kernel: 2 edges per thread (eA = blk*512+t, eB = eA+256).
__global__ __launch_bounds__(256) void csr_edge_kernel(
    const void* __restrict__ x,
    const void* __restrict__ ei,
    const void* __restrict__ W1,
    const void* __restrict__ b1,
    const void* __restrict__ W2,
    const void* __restrict__ b2,
    const float* __restrict__ prep,
    int* __restrict__ wsI)
{
    __shared__ __align__(16) float sW1f[HID * 2 * D];   // f32 path only
    __shared__ __align__(16) float sW2tf[HID * D];      // f32 path only
    __shared__ float sb1[HID];
    __shared__ float sb2[D];
    __shared__ int sfl[2];

    detect_flags_par(x, ei, sfl);
    __syncthreads();
    int f32 = sfl[0], i64 = sfl[1];
    int t = threadIdx.x;

    if (f32) {
        stage_weights(W1, b1, W2, b2, 1, sW1f, sW2tf, sb1, sb2);
        __syncthreads();
    }

    int eA = blockIdx.x * 512 + t;
    int eB = eA + 256;
    if (eA >= N_EDGES) return;
    bool hasB = (eB < N_EDGES);

    int sA, dA;
    load_edge(ei, eA, i64, sA, dA);
    int sB = 0, dB = 0;
    if (hasB) load_edge(ei, eB, i64, sB, dB);   // else dummy edge 0->0 (safe)

    float degsA = (float)wsI[DEG_OFF + sA];
    float degdA = (float)wsI[DEG_OFF + dA];
    float coefA = (1.0f / sqrtf(fmaxf(degsA, 1e-5f))) * (1.0f / sqrtf(fmaxf(degdA, 1e-5f)));
    float degsB = (float)wsI[DEG_OFF + sB];
    float degdB = (float)wsI[DEG_OFF + dB];
    float coefB = (1.0f / sqrtf(fmaxf(degsB, 1e-5f))) * (1.0f / sqrtf(fmaxf(degdB, 1e-5f)));

    float* msg = (float*)(wsI + MSG_OFF_I);

    float xsA[D], xdA[D], xsB[D], xdB[D];
    load16(x, (long long)sA * D, f32, xsA);
    load16(x, (long long)dA * D, f32, xdA);
    load16(x, (long long)sB * D, f32, xsB);
    load16(x, (long long)dB * D, f32, xdB);

    float msA[D], mdA[D], msB[D], mdB[D];
    if (!f32) {
        edge_math_prep2(prep, xsA, xdA, coefA, xsB, xdB, coefB,
                        msA, mdA, msB, mdB);
    } else {
        edge_math_v4(sW1f, sW2tf, sb1, sb2, xsA, xdA, coefA, msA, mdA);
        if (hasB)
            edge_math_v4(sW1f, sW2tf, sb1, sb2, xsB, xdB, coefB, msB, mdB);
    }

    write_msgs(wsI, msg, sA, dA, msA, mdA);
    if (hasB) write_msgs(wsI, msg, sB, dB, msB, mdB);
}

__global__ __launch_bounds__(256) void csr_gather_kernel(
    const void* __restrict__ x,
    const void* __restrict__ ei,
    const int* __restrict__ wsI,
    void* __restrict__ out)
{
    __shared__ int sfl[2];
    detect_flags_par(x, ei, sfl);
    __syncthreads();
    int f32 = sfl[0];

    int n = blockIdx.x * 64 + (threadIdx.x >> 2);
    int c = threadIdx.x & 3;
    if (n >= N_NODES) return;
    gather_node(n, c, f32, wsI, x, out);
}

// ===========================================================================
// Fallback path (tiny workspace): float atomics into acc (known-good)
// ===========================================================================
__global__ void fb_init_kernel(float* __restrict__ ws,
                               const void* __restrict__ x,
                               const void* __restrict__ ei) {
    int i = blockIdx.x * blockDim.x + threadIdx.x;
    if (i < FB_FLAGS) ws[i] = 0.0f;
    if (blockIdx.x == 0)
        detect_flags_par(x, ei, (int*)(ws + FB_FLAGS));
}

__global__ void fb_deg_kernel(const void* __restrict__ ei, float* __restrict__ ws) {
    int i64 = ((const int*)(ws + FB_FLAGS))[1];
    int e = blockIdx.x * blockDim.x + threadIdx.x;
    if (e >= N_EDGES) return;
    int s, d;
    load_edge(ei, e, i64, s, d);
    atomicAdd(&ws[s], 1.0f);
    atomicAdd(&ws[d], 1.0f);
}

__global__ __launch_bounds__(256) void fb_edge_kernel(
    const void* __restrict__ x, const void* __restrict__ ei,
    const void* __restrict__ W1, const void* __restrict__ b1,
    const void* __restrict__ W2, const void* __restrict__ b2,
    float* __restrict__ ws)
{
    __shared__ __align__(16) float sW1[HID * 2 * D];
    __shared__ __align__(16) float sW2t[HID * D];
    __shared__ float sb1[HID];
    __shared__ float sb2[D];
    const int* flags = (const int*)(ws + FB_FLAGS);
    int f32 = flags[0], i64 = flags[1];
    stage_weights(W1, b1, W2, b2, f32, sW1, sW2t, sb1, sb2);
    __syncthreads();
    int e = blockIdx.x * blockDim.x + threadIdx.x;
    if (e >= N_EDGES) return;
    int s, d;
    load_edge(ei, e, i64, s, d);
    float xs[D], xd[D];
    load16(x, (long long)s * D, f32, xs);
    load16(x, (long long)d * D, f32, xd);
    float coef = (1.0f / sqrtf(fmaxf(ws[s], 1e-5f))) * (1.0f / sqrtf(fmaxf(ws[d], 1e-5f)));
    float ms[D], md[D];
    edge_math_v4(sW1, sW2t, sb1, sb2, xs, xd, coef, ms, md);
    float* acc = ws + FB_NDEG;
#pragma unroll
    for (int i = 0; i < D; i++) atomicAdd(&acc[(long long)s * D + i], ms[i]);
#pragma unroll
    for (int i = 0; i < D; i++) atomicAdd(&acc[(long long)d * D + i], md[i]);
}

__global__ void fb_finalize_kernel(const void* __restrict__ x,
                                   const float* __restrict__ ws,
                                   void* __restrict__ out)
{
    int f32 = ((const int*)(ws + FB_FLAGS))[0];
    const float* acc = ws + FB_NDEG;
    int i = blockIdx.x * blockDim.x + threadIdx.x;
    if (i >= FB_NACC) return;
    float v = ld_f(x, i, f32) + acc[i];
    v = fmaxf(v, 0.0f);
    if (f32) ((float*)out)[i] = v;
    else     ((__hip_bfloat16*)out)[i] = __float2bfloat16(v);
}

// ===========================================================================
extern "C" void kernel_launch(void* const* d_in, const int* in_sizes, int n_in,
                              void* d_out, int out_size, void* d_ws, size_t ws_size,
                              hipStream_t stream)
{
    const void* x  = d_in[0];
    const void* ei = d_in[1];
    const void* W1 = d_in[2];
    const void* b1 = d_in[3];
    const void* W2 = d_in[4];
    const void* b2 = d_in[5];

    int blk = 256;
    if (ws_size >= CSR_NEEDED_BYTES) {
        int* wsI = (int*)d_ws;
        hipMemsetAsync(d_ws, 0, (size_t)4 * N_NODES * sizeof(int), stream);
        csr_count_kernel<<<(N_EDGES + blk - 1) / blk, blk, 0, stream>>>(
            ei, x, W1, b1, W2, b2, wsI);
        csr_scan1_kernel<<<SCAN_G, SCAN_B, 0, stream>>>(wsI);
        csr_scan3_kernel<<<SCAN_G, SCAN_B, 0, stream>>>(wsI);
        csr_edge_kernel<<<(N_EDGES + 511) / 512, blk, 0, stream>>>(
            x, ei, W1, b1, W2, b2, (const float*)(wsI + PREP_OFF), wsI);
        csr_gather_kernel<<<(N_NODES + 63) / 64, blk, 0, stream>>>(x, ei, wsI, d_out);
    } else {
        float* ws = (float*)d_ws;
        fb_init_kernel<<<(FB_FLAGS + blk - 1) / blk, blk, 0, stream>>>(ws, x, ei);
        fb_deg_kernel<<<(N_EDGES + blk - 1) / blk, blk, 0, stream>>>(ei, ws);
        fb_edge_kernel<<<(N_EDGES + blk - 1) / blk, blk, 0, stream>>>(x, ei, W1, b1, W2, b2, ws);
        fb_finalize_kernel<<<(FB_NACC + blk - 1) / blk, blk, 0, stream>>>(x, ws, d_out);
    }
}

// Round 9
// 205.823 us; speedup vs baseline: 1.3950x; 1.3950x over previous
//
#include <hip/hip_runtime.h>
#include <hip/hip_bf16.h>
#include <hip/hip_fp16.h>

#define N_NODES 50000
#define N_EDGES 400000
#define D 16
#define HID 64

#define SCAN_B 256
#define SCAN_G ((N_NODES + SCAN_B - 1) / SCAN_B)   // 196

typedef unsigned short ushort_t;

// ---------------- int-indexed workspace layout ----------------
#define CNT4_OFF  0                       // [4][N] replicated counts (memset 0)
#define DEG_OFF   (4 * N_NODES)           // [N] total degree
#define OFF_OFF   (5 * N_NODES)           // [N+1] CSR offsets
#define CUR_OFF   (6 * N_NODES + 1)       // [N] claim cursors
#define BS_OFF    (7 * N_NODES + 1)       // [SCAN_G] block sums
#define MSG_OFF_I (((BS_OFF + SCAN_G) + 15) & ~15) // [2E*16] fp32 msgs, 64B rows
// prep region: [0..4095] old-style table (64 j-rows x 64 dw: W1|W2|b1),
//              [4096..4111] b2 (shared), [4112..5135] W2T[j][i] f32 (new path)
#define PREP_OFF  (MSG_OFF_I + 2 * N_EDGES * D)
#define PREP_DW   (64 * 64 + 16 + 64 * 16)
// AB table (new path): [N][128] f32 = A'[0..63] (W1_left.x + b1), B[64..127]
#define AB_OFF    (PREP_OFF + PREP_DW)
#define AB_DW     (N_NODES * 2 * HID)
#define CSR_NEEDED_BYTES ((size_t)(AB_OFF) * 4 + 64)
#define NEW_NEEDED_BYTES ((size_t)(AB_OFF + AB_DW) * 4 + 64)

// ---------------- fallback (atomic) layout ----------------
#define FB_NDEG   (N_NODES)
#define FB_NACC   (N_NODES * D)
#define FB_FLAGS  (FB_NDEG + FB_NACC)

// ---------------------------------------------------------------------------
// dtype helpers
// ---------------------------------------------------------------------------
__device__ __forceinline__ float bf_bits(ushort_t us) {
    return __uint_as_float(((unsigned)us) << 16);
}
__device__ __forceinline__ float lo_bf(unsigned u) { return __uint_as_float(u << 16); }
__device__ __forceinline__ float hi_bf(unsigned u) { return __uint_as_float(u & 0xffff0000u); }
__device__ __forceinline__ ushort_t f2bf(float v) {
    unsigned u = __float_as_uint(v);
    unsigned r = (u + 0x7fffu + ((u >> 16) & 1u)) >> 16;
    return (ushort_t)r;
}
__device__ __forceinline__ float ld_f(const void* p, int idx, int f32) {
    return f32 ? ((const float*)p)[idx]
               : bf_bits(((const ushort_t*)p)[idx]);
}

__device__ __forceinline__ void load16(const void* __restrict__ p, long long base,
                                       int f32, float* o) {
    if (f32) {
        const float4* q = (const float4*)((const float*)p + base);
        float4 a = q[0], b = q[1], c = q[2], d = q[3];
        o[0]=a.x; o[1]=a.y; o[2]=a.z; o[3]=a.w;
        o[4]=b.x; o[5]=b.y; o[6]=b.z; o[7]=b.w;
        o[8]=c.x; o[9]=c.y; o[10]=c.z; o[11]=c.w;
        o[12]=d.x; o[13]=d.y; o[14]=d.z; o[15]=d.w;
    } else {
        const uint4* q = (const uint4*)((const ushort_t*)p + base);
        uint4 a = q[0], b = q[1];
        unsigned u[8] = {a.x, a.y, a.z, a.w, b.x, b.y, b.z, b.w};
#pragma unroll
        for (int k = 0; k < 8; k++) {
            o[2 * k]     = lo_bf(u[k]);
            o[2 * k + 1] = hi_bf(u[k]);
        }
    }
}

__device__ __forceinline__ void load_edge(const void* __restrict__ ei, int e, int is64,
                                          int& s, int& d) {
    if (is64) {
        const long long* p = (const long long*)ei;
        s = (int)p[e];
        d = (int)p[N_EDGES + e];
    } else {
        const int* p = (const int*)ei;
        s = p[e];
        d = p[N_EDGES + e];
    }
}

// Parallel flag detection (wave 0, ballot), per-block, no cross-block dep.
__device__ __forceinline__ void detect_flags_par(const void* x, const void* ei,
                                                 int* flags) {
    int t = threadIdx.x;
    if (t < 64) {
        const ushort_t* h = (const ushort_t*)x;
        int bad = 0;
#pragma unroll
        for (int k = 0; k < 4; k++) {
            float v = bf_bits(h[4 * t + k]);
            if (!(v == v) || fabsf(v) > 1.0e6f) bad = 1;
        }
        unsigned long long mb = __ballot(bad);
        const long long* p = (const long long*)ei;
        int bad64 = 0;
        if (t < 16) {
            long long v = p[t];
            bad64 = (v < 0 || v >= N_NODES) ? 1 : 0;
        }
        unsigned long long m64 = __ballot(bad64);
        if (t == 0) {
            flags[0] = mb ? 1 : 0;
            flags[1] = m64 ? 0 : 1;
        }
    }
}

__device__ __forceinline__ void stage_weights(
    const void* W1, const void* b1, const void* W2, const void* b2, int f32,
    float* sW1, float* sW2t, float* sb1, float* sb2)
{
    int t = threadIdx.x;
    for (int idx = t; idx < HID * 2 * D; idx += blockDim.x)
        sW1[idx] = ld_f(W1, idx, f32);
    for (int idx = t; idx < HID * D; idx += blockDim.x) {
        int j = idx / D, i = idx % D;
        sW2t[idx] = ld_f(W2, i * HID + j, f32);
    }
    if (t < HID) sb1[t] = ld_f(b1, t, f32);
    if (t < D)  sb2[t] = ld_f(b2, t, f32);
}

// ---------------------------------------------------------------------------
// Full-MLP per-edge math, f32 (safety + fallback paths) — proven op order.
// ---------------------------------------------------------------------------
__device__ __forceinline__ void edge_math_v4(
    const float* __restrict__ sW1, const float* __restrict__ sW2t,
    const float* __restrict__ sb1, const float* __restrict__ sb2,
    const float* xs, const float* xd, float coef,
    float* ms, float* md)
{
    float vs[D], vd[D];
#pragma unroll
    for (int i = 0; i < D; i++) { vs[i] = sb2[i]; vd[i] = sb2[i]; }
#pragma unroll 4
    for (int j = 0; j < HID; j++) {
        float hs = sb1[j], hd = sb1[j];
        const float4* w4 = (const float4*)&sW1[j * 2 * D];
#pragma unroll
        for (int t = 0; t < 4; t++) {
            float4 wv = w4[t];
            int k = 4 * t;
            hs = fmaf(wv.x, xs[k],     hs); hd = fmaf(wv.x, xd[k],     hd);
            hs = fmaf(wv.y, xs[k + 1], hs); hd = fmaf(wv.y, xd[k + 1], hd);
            hs = fmaf(wv.z, xs[k + 2], hs); hd = fmaf(wv.z, xd[k + 2], hd);
            hs = fmaf(wv.w, xs[k + 3], hs); hd = fmaf(wv.w, xd[k + 3], hd);
        }
#pragma unroll
        for (int t = 0; t < 4; t++) {
            float4 wv = w4[4 + t];
            int k = 4 * t;
            hs = fmaf(wv.x, xd[k],     hs); hd = fmaf(wv.x, xs[k],     hd);
            hs = fmaf(wv.y, xd[k + 1], hs); hd = fmaf(wv.y, xs[k + 1], hd);
            hs = fmaf(wv.z, xd[k + 2], hs); hd = fmaf(wv.z, xs[k + 2], hd);
            hs = fmaf(wv.w, xd[k + 3], hs); hd = fmaf(wv.w, xs[k + 3], hd);
        }
        hs = fmaxf(hs, 0.0f);
        hd = fmaxf(hd, 0.0f);
        const float4* w24 = (const float4*)&sW2t[j * D];
#pragma unroll
        for (int t = 0; t < 4; t++) {
            float4 u = w24[t];
            int i = 4 * t;
            vs[i]     = fmaf(u.x, hs, vs[i]);     vd[i]     = fmaf(u.x, hd, vd[i]);
            vs[i + 1] = fmaf(u.y, hs, vs[i + 1]); vd[i + 1] = fmaf(u.y, hd, vd[i + 1]);
            vs[i + 2] = fmaf(u.z, hs, vs[i + 2]); vd[i + 2] = fmaf(u.z, hd, vd[i + 2]);
            vs[i + 3] = fmaf(u.w, hs, vs[i + 3]); vd[i + 3] = fmaf(u.w, hd, vd[i + 3]);
        }
    }
    float ns = 0.0f, nd = 0.0f;
#pragma unroll
    for (int i = 0; i < D; i++) { ns = fmaf(vs[i], vs[i], ns); nd = fmaf(vd[i], vd[i], nd); }
    float is_ = 1.0f / fmaxf(sqrtf(ns), 1e-12f);
    float id_ = 1.0f / fmaxf(sqrtf(nd), 1e-12f);
#pragma unroll
    for (int i = 0; i < D; i++) { vs[i] *= is_; vd[i] *= id_; }
    float dot1 = 0.0f;
#pragma unroll
    for (int i = 0; i < D; i++) dot1 = fmaf(vd[i], xd[i], dot1);
#pragma unroll
    for (int i = 0; i < D; i++) ms[i] = fmaf(-2.0f * dot1, vd[i], xd[i]);
    float dot2 = 0.0f;
#pragma unroll
    for (int i = 0; i < D; i++) dot2 = fmaf(vs[i], ms[i], dot2);
#pragma unroll
    for (int i = 0; i < D; i++) ms[i] = coef * fmaf(-2.0f * dot2, vs[i], ms[i]);
    float dot3 = 0.0f;
#pragma unroll
    for (int i = 0; i < D; i++) dot3 = fmaf(vs[i], xs[i], dot3);
#pragma unroll
    for (int i = 0; i < D; i++) md[i] = fmaf(-2.0f * dot3, vs[i], xs[i]);
    float dot4 = 0.0f;
#pragma unroll
    for (int i = 0; i < D; i++) dot4 = fmaf(vd[i], md[i], dot4);
#pragma unroll
    for (int i = 0; i < D; i++) md[i] = coef * fmaf(-2.0f * dot4, vd[i], md[i]);
}

// ---------------------------------------------------------------------------
// Old-tier bf16 edge math on SGPR table (R3/R6-proven; workspace-limited tier)
// ---------------------------------------------------------------------------
__device__ __forceinline__ void edge_math_prep(
    const float* __restrict__ prep,
    const float* xs, const float* xd, float coef,
    float* ms, float* md)
{
    const float* b2f = prep + 64 * 64;
    float vs[D], vd[D];
#pragma unroll
    for (int i = 0; i < D; i++) { vs[i] = b2f[i]; vd[i] = b2f[i]; }

#pragma unroll 1
    for (int j = 0; j < HID; j++) {
        const float* w = prep + (j << 6);
        float b1j = w[48];
        float hs0 = b1j, hs1 = 0.0f, hd0 = b1j, hd1 = 0.0f;
#pragma unroll
        for (int k = 0; k < 8; k++) {
            hs0 = fmaf(w[k],     xs[k],     hs0);
            hd0 = fmaf(w[k],     xd[k],     hd0);
            hs1 = fmaf(w[8 + k], xs[8 + k], hs1);
            hd1 = fmaf(w[8 + k], xd[8 + k], hd1);
        }
#pragma unroll
        for (int k = 0; k < 8; k++) {
            hs0 = fmaf(w[16 + k], xd[k],     hs0);
            hd0 = fmaf(w[16 + k], xs[k],     hd0);
            hs1 = fmaf(w[24 + k], xd[8 + k], hs1);
            hd1 = fmaf(w[24 + k], xs[8 + k], hd1);
        }
        float hs = fmaxf(hs0 + hs1, 0.0f);
        float hd = fmaxf(hd0 + hd1, 0.0f);
#pragma unroll
        for (int i = 0; i < D; i++) {
            vs[i] = fmaf(w[32 + i], hs, vs[i]);
            vd[i] = fmaf(w[32 + i], hd, vd[i]);
        }
    }

    float ns = 0.0f, nd = 0.0f;
#pragma unroll
    for (int i = 0; i < D; i++) { ns = fmaf(vs[i], vs[i], ns); nd = fmaf(vd[i], vd[i], nd); }
    float is_ = 1.0f / fmaxf(sqrtf(ns), 1e-12f);
    float id_ = 1.0f / fmaxf(sqrtf(nd), 1e-12f);
#pragma unroll
    for (int i = 0; i < D; i++) { vs[i] *= is_; vd[i] *= id_; }

    float dot1 = 0.0f;
#pragma unroll
    for (int i = 0; i < D; i++) dot1 = fmaf(vd[i], xd[i], dot1);
#pragma unroll
    for (int i = 0; i < D; i++) ms[i] = fmaf(-2.0f * dot1, vd[i], xd[i]);
    float dot2 = 0.0f;
#pragma unroll
    for (int i = 0; i < D; i++) dot2 = fmaf(vs[i], ms[i], dot2);
#pragma unroll
    for (int i = 0; i < D; i++) ms[i] = coef * fmaf(-2.0f * dot2, vs[i], ms[i]);
    float dot3 = 0.0f;
#pragma unroll
    for (int i = 0; i < D; i++) dot3 = fmaf(vs[i], xs[i], dot3);
#pragma unroll
    for (int i = 0; i < D; i++) md[i] = fmaf(-2.0f * dot3, vs[i], xs[i]);
    float dot4 = 0.0f;
#pragma unroll
    for (int i = 0; i < D; i++) dot4 = fmaf(vd[i], md[i], dot4);
#pragma unroll
    for (int i = 0; i < D; i++) md[i] = coef * fmaf(-2.0f * dot4, vd[i], md[i]);
}

// Edge tail: claim slots + write both msgs.
__device__ __forceinline__ void write_msgs(int* __restrict__ wsI, float* __restrict__ msg,
                                           int s, int d, const float* ms, const float* md)
{
    int slot_s = atomicAdd(&wsI[CUR_OFF + s], 1);
    float4* m0 = (float4*)(msg + (long long)slot_s * D);
    m0[0] = make_float4(ms[0], ms[1], ms[2], ms[3]);
    m0[1] = make_float4(ms[4], ms[5], ms[6], ms[7]);
    m0[2] = make_float4(ms[8], ms[9], ms[10], ms[11]);
    m0[3] = make_float4(ms[12], ms[13], ms[14], ms[15]);
    int slot_d = atomicAdd(&wsI[CUR_OFF + d], 1);
    float4* m1 = (float4*)(msg + (long long)slot_d * D);
    m1[0] = make_float4(md[0], md[1], md[2], md[3]);
    m1[1] = make_float4(md[4], md[5], md[6], md[7]);
    m1[2] = make_float4(md[8], md[9], md[10], md[11]);
    m1[3] = make_float4(md[12], md[13], md[14], md[15]);
}

// Weight-table packing: old 64x64 table + b2 + new W2T[j][i] block.
__device__ __forceinline__ void pack_prep(const void* W1, const void* b1,
                                          const void* W2, const void* b2,
                                          int* __restrict__ wsI)
{
    float* pf = (float*)(wsI + PREP_OFF);
    const ushort_t* W1b = (const ushort_t*)W1;
    const ushort_t* W2b = (const ushort_t*)W2;
    const ushort_t* b1b = (const ushort_t*)b1;
    const ushort_t* b2b = (const ushort_t*)b2;
    for (int idx = threadIdx.x; idx < 64 * 64; idx += 256) {
        int j = idx >> 6, w = idx & 63;
        float val = 0.0f;
        if (w < 32)      val = bf_bits(W1b[j * 32 + w]);
        else if (w < 48) val = bf_bits(W2b[(w - 32) * HID + j]);
        else if (w == 48) val = bf_bits(b1b[j]);
        pf[idx] = val;
    }
    if (threadIdx.x < D)
        pf[64 * 64 + threadIdx.x] = bf_bits(b2b[threadIdx.x]);
    // new-path W2T: [j][i] at 4112
    for (int idx = threadIdx.x; idx < HID * D; idx += 256) {
        int j = idx >> 4, i = idx & 15;
        pf[64 * 64 + 16 + idx] = bf_bits(W2b[i * HID + j]);
    }
}

// Gather body for one (node, quad) pair.
__device__ __forceinline__ void gather_node(int n, int c, int f32,
                                            const int* __restrict__ wsI,
                                            const void* __restrict__ x,
                                            void* __restrict__ out)
{
    const int* off = wsI + OFF_OFF;
    const float4* msg4 = (const float4*)(wsI + MSG_OFF_I);

    int beg = off[n], end = off[n + 1];
    float4 a = make_float4(0.0f, 0.0f, 0.0f, 0.0f);
    int it = beg;
    for (; it + 2 <= end; it += 2) {
        float4 u = msg4[(long long)it * 4 + c];
        float4 v = msg4[(long long)(it + 1) * 4 + c];
        a.x += u.x + v.x; a.y += u.y + v.y; a.z += u.z + v.z; a.w += u.w + v.w;
    }
    if (it < end) {
        float4 u = msg4[(long long)it * 4 + c];
        a.x += u.x; a.y += u.y; a.z += u.z; a.w += u.w;
    }

    long long xb = (long long)n * D + 4 * c;
    float4 xv;
    if (f32) {
        xv = *(const float4*)((const float*)x + xb);
    } else {
        uint2 u = *(const uint2*)((const ushort_t*)x + xb);
        xv.x = lo_bf(u.x); xv.y = hi_bf(u.x);
        xv.z = lo_bf(u.y); xv.w = hi_bf(u.y);
    }
    float4 r;
    r.x = fmaxf(xv.x + a.x, 0.0f);
    r.y = fmaxf(xv.y + a.y, 0.0f);
    r.z = fmaxf(xv.z + a.z, 0.0f);
    r.w = fmaxf(xv.w + a.w, 0.0f);
    if (f32) {
        *(float4*)((float*)out + xb) = r;
    } else {
        uint2 o;
        o.x = (unsigned)f2bf(r.x) | ((unsigned)f2bf(r.y) << 16);
        o.y = (unsigned)f2bf(r.z) | ((unsigned)f2bf(r.w) << 16);
        *(uint2*)((ushort_t*)out + xb) = o;
    }
}

// ===========================================================================
// CSR pipeline
// ===========================================================================
__global__ void csr_count_kernel(const void* __restrict__ ei,
                                 const void* __restrict__ x,
                                 const void* __restrict__ W1,
                                 const void* __restrict__ b1,
                                 const void* __restrict__ W2,
                                 const void* __restrict__ b2,
                                 int* __restrict__ wsI) {
    __shared__ int sfl[2];
    detect_flags_par(x, ei, sfl);
    __syncthreads();
    int i64 = sfl[1];

    if (blockIdx.x == 0) pack_prep(W1, b1, W2, b2, wsI);

    int e = blockIdx.x * blockDim.x + threadIdx.x;
    if (e >= N_EDGES) return;
    int s, d;
    load_edge(ei, e, i64, s, d);
    int r = (e & 3) * N_NODES;
    atomicAdd(&wsI[CNT4_OFF + r + s], 1);
    atomicAdd(&wsI[CNT4_OFF + r + d], 1);
}

// scan1 + (new tier) per-node MLP part-1: A'[n] = W1_left.x[n] + b1,
// B[n] = W1_right.x[n]. One thread per node; W1 rows are wave-uniform
// s_loads; removes 4096 of 6144 FMAs from EVERY edge (deg~16 reuse).
__global__ __launch_bounds__(SCAN_B) void csr_scan1_kernel(
    int* __restrict__ wsI,
    const void* __restrict__ x,
    const void* __restrict__ ei,
    const void* __restrict__ W1,
    const void* __restrict__ b1,
    int useAB)
{
    __shared__ int sm[SCAN_B];
    __shared__ int sfl[2];
    detect_flags_par(x, ei, sfl);
    __syncthreads();
    int f32 = sfl[0];

    int t = threadIdx.x;
    int g = blockIdx.x * SCAN_B + t;
    int c = 0;
    if (g < N_NODES) {
        c = wsI[CNT4_OFF + g] + wsI[CNT4_OFF + N_NODES + g]
          + wsI[CNT4_OFF + 2 * N_NODES + g] + wsI[CNT4_OFF + 3 * N_NODES + g];
        wsI[DEG_OFF + g] = c;
    }
    sm[t] = c;
    __syncthreads();
    for (int st = SCAN_B / 2; st > 0; st >>= 1) {
        if (t < st) sm[t] += sm[t + st];
        __syncthreads();
    }
    if (t == 0) wsI[BS_OFF + blockIdx.x] = sm[0];

    // ---- node MLP part-1 (no further syncs; bf16 tier only) ----
    if (useAB && !f32 && g < N_NODES) {
        const ushort_t* b1b = (const ushort_t*)b1;
        const unsigned* W1w = (const unsigned*)W1;    // 16 dwords per j-row
        float xr[D];
        load16(x, (long long)g * D, 0, xr);
        float* ab = (float*)(wsI + AB_OFF) + (long long)g * 2 * HID;
#pragma unroll 1
        for (int j4 = 0; j4 < 16; j4++) {
            float4 a4, b4;
#pragma unroll
            for (int r = 0; r < 4; r++) {
                int j = 4 * j4 + r;
                const unsigned* w = W1w + j * 16;     // uniform -> s_load
                float a = bf_bits(b1b[j]);
                float bb = 0.0f;
#pragma unroll
                for (int k = 0; k < 8; k++) {         // cols 0..15 -> A
                    unsigned wk = w[k];
                    a = fmaf(lo_bf(wk), xr[2 * k],     a);
                    a = fmaf(hi_bf(wk), xr[2 * k + 1], a);
                }
#pragma unroll
                for (int k = 0; k < 8; k++) {         // cols 16..31 -> B
                    unsigned wk = w[8 + k];
                    bb = fmaf(lo_bf(wk), xr[2 * k],     bb);
                    bb = fmaf(hi_bf(wk), xr[2 * k + 1], bb);
                }
                (&a4.x)[r] = a;
                (&b4.x)[r] = bb;
            }
            *(float4*)(ab + 4 * j4)       = a4;
            *(float4*)(ab + HID + 4 * j4) = b4;
        }
    }
}

__global__ __launch_bounds__(SCAN_B) void csr_scan3_kernel(int* __restrict__ wsI) {
    __shared__ int sB[SCAN_B];
    __shared__ int sm[SCAN_B];
    int t = threadIdx.x;
    int bsv = (t < SCAN_G) ? wsI[BS_OFF + t] : 0;
    sB[t] = bsv;
    __syncthreads();
    for (int st = 1; st < SCAN_B; st <<= 1) {
        int u = (t >= st) ? sB[t - st] : 0;
        __syncthreads();
        sB[t] += u;
        __syncthreads();
    }
    int blockBase = sB[blockIdx.x] - wsI[BS_OFF + blockIdx.x];

    int g = blockIdx.x * SCAN_B + t;
    int c = (g < N_NODES) ? wsI[DEG_OFF + g] : 0;
    sm[t] = c;
    __syncthreads();
    for (int st = 1; st < SCAN_B; st <<= 1) {
        int u = (t >= st) ? sm[t - st] : 0;
        __syncthreads();
        sm[t] += u;
        __syncthreads();
    }
    int excl = sm[t] - c + blockBase;
    if (g < N_NODES) {
        wsI[OFF_OFF + g] = excl;
        wsI[CUR_OFF + g] = excl;
        if (g == N_NODES - 1) wsI[OFF_OFF + N_NODES] = excl + c;
    }
}

// Edge kernel. New tier (useAB): h_s = relu(A'[s]+B[d]), h_d = relu(A'[d]+B[s])
// read from the AB table -> only GEMM2 (2048 FMA) + epilogue per edge.
// VALU-busy model: ~2600 src ops vs 6400 -> ~25us total (was a constant 60us
// across R0/R2/R3/R6/R8). AB traffic 1KB/edge = 400MB via L2/L3 (25.6MB set).
__global__ __launch_bounds__(256) void csr_edge_kernel(
    const void* __restrict__ x,
    const void* __restrict__ ei,
    const void* __restrict__ W1,
    const void* __restrict__ b1,
    const void* __restrict__ W2,
    const void* __restrict__ b2,
    const float* __restrict__ prep,
    int* __restrict__ wsI,
    int useAB)
{
    __shared__ __align__(16) float sW1f[HID * 2 * D];   // f32 path only
    __shared__ __align__(16) float sW2tf[HID * D];      // f32 path only
    __shared__ float sb1[HID];
    __shared__ float sb2[D];
    __shared__ int sfl[2];

    detect_flags_par(x, ei, sfl);
    __syncthreads();
    int f32 = sfl[0], i64 = sfl[1];
    int t = threadIdx.x;

    if (f32) {
        stage_weights(W1, b1, W2, b2, 1, sW1f, sW2tf, sb1, sb2);
        __syncthreads();
    }

    int e = blockIdx.x * 256 + t;
    if (e >= N_EDGES) return;

    int s, d;
    load_edge(ei, e, i64, s, d);
    float degs = (float)wsI[DEG_OFF + s];
    float degd = (float)wsI[DEG_OFF + d];
    float coef = (1.0f / sqrtf(fmaxf(degs, 1e-5f))) * (1.0f / sqrtf(fmaxf(degd, 1e-5f)));
    float* msg = (float*)(wsI + MSG_OFF_I);

    if (!f32 && useAB) {
        const float* AB = (const float*)(wsI + AB_OFF);
        const float* ns_ = AB + (long long)s * 2 * HID;   // A'[s] | B[s]
        const float* nd_ = AB + (long long)d * 2 * HID;   // A'[d] | B[d]
        const float* b2f = prep + 64 * 64;
        const float* w2t = prep + 64 * 64 + 16;

        float vs[D], vd[D];
#pragma unroll
        for (int i = 0; i < D; i++) { vs[i] = b2f[i]; vd[i] = b2f[i]; }

#pragma unroll 1
        for (int jj = 0; jj < 16; jj++) {
            float4 as4 = *(const float4*)(ns_ + 4 * jj);
            float4 bs4 = *(const float4*)(ns_ + HID + 4 * jj);
            float4 ad4 = *(const float4*)(nd_ + 4 * jj);
            float4 bd4 = *(const float4*)(nd_ + HID + 4 * jj);
#pragma unroll
            for (int r = 0; r < 4; r++) {
                const float* w2 = w2t + (4 * jj + r) * D;   // uniform -> s_load
                float hs = fmaxf((&as4.x)[r] + (&bd4.x)[r], 0.0f);
                float hd = fmaxf((&ad4.x)[r] + (&bs4.x)[r], 0.0f);
#pragma unroll
                for (int i = 0; i < D; i++) {
                    vs[i] = fmaf(w2[i], hs, vs[i]);
                    vd[i] = fmaf(w2[i], hd, vd[i]);
                }
            }
        }

        // epilogue (load x late to cut VGPR live range)
        float xs[D], xd[D];
        load16(x, (long long)s * D, 0, xs);
        load16(x, (long long)d * D, 0, xd);

        float ns = 0.0f, nd = 0.0f;
#pragma unroll
        for (int i = 0; i < D; i++) { ns = fmaf(vs[i], vs[i], ns); nd = fmaf(vd[i], vd[i], nd); }
        float is_ = 1.0f / fmaxf(sqrtf(ns), 1e-12f);
        float id_ = 1.0f / fmaxf(sqrtf(nd), 1e-12f);
#pragma unroll
        for (int i = 0; i < D; i++) { vs[i] *= is_; vd[i] *= id_; }

        float ms[D], md[D];
        float dot1 = 0.0f;
#pragma unroll
        for (int i = 0; i < D; i++) dot1 = fmaf(vd[i], xd[i], dot1);
#pragma unroll
        for (int i = 0; i < D; i++) ms[i] = fmaf(-2.0f * dot1, vd[i], xd[i]);
        float dot2 = 0.0f;
#pragma unroll
        for (int i = 0; i < D; i++) dot2 = fmaf(vs[i], ms[i], dot2);
#pragma unroll
        for (int i = 0; i < D; i++) ms[i] = coef * fmaf(-2.0f * dot2, vs[i], ms[i]);
        float dot3 = 0.0f;
#pragma unroll
        for (int i = 0; i < D; i++) dot3 = fmaf(vs[i], xs[i], dot3);
#pragma unroll
        for (int i = 0; i < D; i++) md[i] = fmaf(-2.0f * dot3, vs[i], xs[i]);
        float dot4 = 0.0f;
#pragma unroll
        for (int i = 0; i < D; i++) dot4 = fmaf(vd[i], md[i], dot4);
#pragma unroll
        for (int i = 0; i < D; i++) md[i] = coef * fmaf(-2.0f * dot4, vd[i], md[i]);

        write_msgs(wsI, msg, s, d, ms, md);
    } else {
        float xs[D], xd[D];
        load16(x, (long long)s * D, f32, xs);
        load16(x, (long long)d * D, f32, xd);
        float ms[D], md[D];
        if (!f32) edge_math_prep(prep, xs, xd, coef, ms, md);
        else      edge_math_v4(sW1f, sW2tf, sb1, sb2, xs, xd, coef, ms, md);
        write_msgs(wsI, msg, s, d, ms, md);
    }
}

__global__ __launch_bounds__(256) void csr_gather_kernel(
    const void* __restrict__ x,
    const void* __restrict__ ei,
    const int* __restrict__ wsI,
    void* __restrict__ out)
{
    __shared__ int sfl[2];
    detect_flags_par(x, ei, sfl);
    __syncthreads();
    int f32 = sfl[0];

    int n = blockIdx.x * 64 + (threadIdx.x >> 2);
    int c = threadIdx.x & 3;
    if (n >= N_NODES) return;
    gather_node(n, c, f32, wsI, x, out);
}

// ===========================================================================
// Fallback path (tiny workspace): float atomics into acc (known-good)
// ===========================================================================
__global__ void fb_init_kernel(float* __restrict__ ws,
                               const void* __restrict__ x,
                               const void* __restrict__ ei) {
    int i = blockIdx.x * blockDim.x + threadIdx.x;
    if (i < FB_FLAGS) ws[i] = 0.0f;
    if (blockIdx.x == 0)
        detect_flags_par(x, ei, (int*)(ws + FB_FLAGS));
}

__global__ void fb_deg_kernel(const void* __restrict__ ei, float* __restrict__ ws) {
    int i64 = ((const int*)(ws + FB_FLAGS))[1];
    int e = blockIdx.x * blockDim.x + threadIdx.x;
    if (e >= N_EDGES) return;
    int s, d;
    load_edge(ei, e, i64, s, d);
    atomicAdd(&ws[s], 1.0f);
    atomicAdd(&ws[d], 1.0f);
}

__global__ __launch_bounds__(256) void fb_edge_kernel(
    const void* __restrict__ x, const void* __restrict__ ei,
    const void* __restrict__ W1, const void* __restrict__ b1,
    const void* __restrict__ W2, const void* __restrict__ b2,
    float* __restrict__ ws)
{
    __shared__ __align__(16) float sW1[HID * 2 * D];
    __shared__ __align__(16) float sW2t[HID * D];
    __shared__ float sb1[HID];
    __shared__ float sb2[D];
    const int* flags = (const int*)(ws + FB_FLAGS);
    int f32 = flags[0], i64 = flags[1];
    stage_weights(W1, b1, W2, b2, f32, sW1, sW2t, sb1, sb2);
    __syncthreads();
    int e = blockIdx.x * blockDim.x + threadIdx.x;
    if (e >= N_EDGES) return;
    int s, d;
    load_edge(ei, e, i64, s, d);
    float xs[D], xd[D];
    load16(x, (long long)s * D, f32, xs);
    load16(x, (long long)d * D, f32, xd);
    float coef = (1.0f / sqrtf(fmaxf(ws[s], 1e-5f))) * (1.0f / sqrtf(fmaxf(ws[d], 1e-5f)));
    float ms[D], md[D];
    edge_math_v4(sW1, sW2t, sb1, sb2, xs, xd, coef, ms, md);
    float* acc = ws + FB_NDEG;
#pragma unroll
    for (int i = 0; i < D; i++) atomicAdd(&acc[(long long)s * D + i], ms[i]);
#pragma unroll
    for (int i = 0; i < D; i++) atomicAdd(&acc[(long long)d * D + i], md[i]);
}

__global__ void fb_finalize_kernel(const void* __restrict__ x,
                                   const float* __restrict__ ws,
                                   void* __restrict__ out)
{
    int f32 = ((const int*)(ws + FB_FLAGS))[0];
    const float* acc = ws + FB_NDEG;
    int i = blockIdx.x * blockDim.x + threadIdx.x;
    if (i >= FB_NACC) return;
    float v = ld_f(x, i, f32) + acc[i];
    v = fmaxf(v, 0.0f);
    if (f32) ((float*)out)[i] = v;
    else     ((__hip_bfloat16*)out)[i] = __float2bfloat16(v);
}

// ===========================================================================
extern "C" void kernel_launch(void* const* d_in, const int* in_sizes, int n_in,
                              void* d_out, int out_size, void* d_ws, size_t ws_size,
                              hipStream_t stream)
{
    const void* x  = d_in[0];
    const void* ei = d_in[1];
    const void* W1 = d_in[2];
    const void* b1 = d_in[3];
    const void* W2 = d_in[4];
    const void* b2 = d_in[5];

    int blk = 256;
    if (ws_size >= CSR_NEEDED_BYTES) {
        int useAB = (ws_size >= NEW_NEEDED_BYTES) ? 1 : 0;
        int* wsI = (int*)d_ws;
        hipMemsetAsync(d_ws, 0, (size_t)4 * N_NODES * sizeof(int), stream);
        csr_count_kernel<<<(N_EDGES + blk - 1) / blk, blk, 0, stream>>>(
            ei, x, W1, b1, W2, b2, wsI);
        csr_scan1_kernel<<<SCAN_G, SCAN_B, 0, stream>>>(wsI, x, ei, W1, b1, useAB);
        csr_scan3_kernel<<<SCAN_G, SCAN_B, 0, stream>>>(wsI);
        csr_edge_kernel<<<(N_EDGES + blk - 1) / blk, blk, 0, stream>>>(
            x, ei, W1, b1, W2, b2, (const float*)(wsI + PREP_OFF), wsI, useAB);
        csr_gather_kernel<<<(N_NODES + 63) / 64, blk, 0, stream>>>(x, ei, wsI, d_out);
    } else {
        float* ws = (float*)d_ws;
        fb_init_kernel<<<(FB_FLAGS + blk - 1) / blk, blk, 0, stream>>>(ws, x, ei);
        fb_deg_kernel<<<(N_EDGES + blk - 1) / blk, blk, 0, stream>>>(ei, ws);
        fb_edge_kernel<<<(N_EDGES + blk - 1) / blk, blk, 0, stream>>>(x, ei, W1, b1, W2, b2, ws);
        fb_finalize_kernel<<<(FB_NACC + blk - 1) / blk, blk, 0, stream>>>(x, ws, d_out);
    }
}